// Round 2
// baseline (1376.295 us; speedup 1.0000x reference)
//
#include <hip/hip_runtime.h>

typedef __attribute__((ext_vector_type(8))) short short8;
typedef __attribute__((ext_vector_type(4))) float f32x4;

__device__ __forceinline__ float silu_f(float x) { return x / (1.0f + __expf(-x)); }

__device__ __forceinline__ unsigned short f2bf(float x) {
  unsigned u = __float_as_uint(x);
  u += 0x7FFFu + ((u >> 16) & 1u);
  return (unsigned short)(u >> 16);
}

// ---------------- generic f32 row-tile GEMM: C = act(A @ W + b) ----------------
// One block owns 64 rows x ALL TN cols -> in-place (C==A) is safe per-row-block.
template<int TN, int ACT>
__global__ __launch_bounds__(256)
void gemm_rowtile(const float* A, const float* __restrict__ W,
                  const float* __restrict__ bias, float* C, int M, int K)
{
  constexpr int NC = TN / 64;
  __shared__ float As[64][17];
  __shared__ float Bs[16][TN + 4];
  const int tid = threadIdx.x;
  const int tx = tid & 15, ty = tid >> 4;
  const int row0 = blockIdx.x * 64;

  float acc[NC][4][4];
#pragma unroll
  for (int c = 0; c < NC; c++)
#pragma unroll
    for (int i = 0; i < 4; i++)
#pragma unroll
      for (int j = 0; j < 4; j++) acc[c][i][j] = 0.f;

  for (int kc = 0; kc < K; kc += 16) {
#pragma unroll
    for (int i = 0; i < 4; i++) {
      int e = tid + 256 * i;
      int r = e >> 4, kk = e & 15;
      int gr = row0 + r;
      As[r][kk] = (gr < M) ? A[(size_t)gr * K + kc + kk] : 0.f;
    }
#pragma unroll
    for (int i = 0; i < TN / 16; i++) {
      int e = tid + 256 * i;
      int kk = e / TN, n = e % TN;
      Bs[kk][n] = W[(size_t)(kc + kk) * TN + n];
    }
    __syncthreads();
#pragma unroll
    for (int kk = 0; kk < 16; kk++) {
      float a[4];
#pragma unroll
      for (int i = 0; i < 4; i++) a[i] = As[ty * 4 + i][kk];
#pragma unroll
      for (int c = 0; c < NC; c++) {
        const float4 b4 = *(const float4*)&Bs[kk][c * 64 + tx * 4];
#pragma unroll
        for (int i = 0; i < 4; i++) {
          acc[c][i][0] += a[i] * b4.x;
          acc[c][i][1] += a[i] * b4.y;
          acc[c][i][2] += a[i] * b4.z;
          acc[c][i][3] += a[i] * b4.w;
        }
      }
    }
    __syncthreads();
  }

#pragma unroll
  for (int c = 0; c < NC; c++)
#pragma unroll
    for (int i = 0; i < 4; i++) {
      int gr = row0 + ty * 4 + i;
      if (gr < M) {
#pragma unroll
        for (int j = 0; j < 4; j++) {
          int col = c * 64 + tx * 4 + j;
          float v = acc[c][i][j] + bias[col];
          if (ACT) v = silu_f(v);
          C[(size_t)gr * TN + col] = v;
        }
      }
    }
}

// ---------------- fused triplet kernel ----------------
// pbuf/ws layouts: bf16, transposed-for-B, XOR chunk swizzle:
//   elem(row,k) at row*128 + (((k>>3) ^ (row&7)) << 3) + (k&7)

__device__ __forceinline__ void gather_p(const float* __restrict__ h,
                                         const float* __restrict__ Mx,
                                         const int* __restrict__ idx_ji,
                                         const int* __restrict__ idx_ki,
                                         unsigned short* pbuf,
                                         int rbase, int T, int tid, int fofs)
{
  const int r = tid >> 3;           // local row 0..63
  const int trow = rbase + r;
  const int cseg = (tid & 7) * 16;  // 16 cols per thread
  if (trow < T) {
    const int ek = idx_ki[trow], ej = idx_ji[trow];
    const float* fa = h + (size_t)ek * 256 + fofs;
    const float* fb = h + (size_t)ej * 256 + fofs;
    const float* mm = Mx + (size_t)trow * 128;
#pragma unroll
    for (int c2 = 0; c2 < 2; c2++) {
      const int c = cseg + 8 * c2;
      float4 a0 = *(const float4*)(fa + c);
      float4 a1 = *(const float4*)(fa + c + 4);
      float4 b0 = *(const float4*)(fb + c);
      float4 b1 = *(const float4*)(fb + c + 4);
      float4 m0 = *(const float4*)(mm + c);
      float4 m1 = *(const float4*)(mm + c + 4);
      short8 o;
      o[0] = (short)f2bf(a0.x * m0.x * b0.x);
      o[1] = (short)f2bf(a0.y * m0.y * b0.y);
      o[2] = (short)f2bf(a0.z * m0.z * b0.z);
      o[3] = (short)f2bf(a0.w * m0.w * b0.w);
      o[4] = (short)f2bf(a1.x * m1.x * b1.x);
      o[5] = (short)f2bf(a1.y * m1.y * b1.y);
      o[6] = (short)f2bf(a1.z * m1.z * b1.z);
      o[7] = (short)f2bf(a1.w * m1.w * b1.w);
      const int chunk = c >> 3;
      *(short8*)(pbuf + r * 128 + ((chunk ^ (r & 7)) << 3)) = o;
    }
  } else {
    short8 z = {0, 0, 0, 0, 0, 0, 0, 0};
#pragma unroll
    for (int c2 = 0; c2 < 2; c2++) {
      const int chunk = (cseg + 8 * c2) >> 3;
      *(short8*)(pbuf + r * 128 + ((chunk ^ (r & 7)) << 3)) = z;
    }
  }
}

__device__ __forceinline__ void mfma_block4(const unsigned short* abuf,
                                            const unsigned short* wsT,
                                            f32x4 (&acc)[4],
                                            int g, int hh, int l15, int l4)
{
  const int arow = 16 * g + l15;
#pragma unroll
  for (int ks = 0; ks < 4; ks++) {
    short8 a = *(const short8*)(abuf + arow * 128 + (((4 * ks + l4) ^ (arow & 7)) << 3));
#pragma unroll
    for (int ct = 0; ct < 4; ct++) {
      const int col = 64 * hh + 16 * ct + l15;
      short8 b = *(const short8*)(wsT + col * 128 + (((4 * ks + l4) ^ (col & 7)) << 3));
      acc[ct] = __builtin_amdgcn_mfma_f32_16x16x32_bf16(a, b, acc[ct], 0, 0, 0);
    }
  }
}

__device__ __forceinline__ void store_s(unsigned short* pbuf, const f32x4 (&acc)[4],
                                        const float* __restrict__ bias,
                                        int g, int hh, int l15, int l4)
{
#pragma unroll
  for (int ct = 0; ct < 4; ct++) {
    const int col = 64 * hh + 16 * ct + l15;
    const float bv = bias[col];
#pragma unroll
    for (int i = 0; i < 4; i++) {
      const int r = 16 * g + 4 * l4 + i;
      float v = silu_f(acc[ct][i] + bv);
      pbuf[r * 128 + ((((col >> 3) ^ (r & 7)) << 3)) + (col & 7)] = f2bf(v);
    }
  }
}

__global__ __launch_bounds__(512, 2)
void triplet_fused(const float* __restrict__ h,
                   const float* __restrict__ M01, const float* __restrict__ M02,
                   const float* __restrict__ Ws01, const float* __restrict__ bs01,
                   const float* __restrict__ Ws02, const float* __restrict__ bs02,
                   const float* __restrict__ Ws,   const float* __restrict__ bs,
                   const int* __restrict__ idx_ji, const int* __restrict__ idx_ki,
                   float* __restrict__ out_acc, int T)
{
  __shared__ unsigned short wsT01[128 * 128];  // 32 KB
  __shared__ unsigned short wsT02[128 * 128];  // 32 KB
  __shared__ unsigned short wsTA[128 * 128];   // 32 KB  (Ws rows 0..127)
  __shared__ unsigned short wsTB[128 * 128];   // 32 KB  (Ws rows 128..255)
  __shared__ unsigned short pbuf[64 * 128];    // 16 KB ping buffer

  const int tid = threadIdx.x;

  // stage weights: W[k][n] f32 -> wsT[n][k] bf16, swizzled
  for (int e = tid; e < 128 * 128; e += 512) {
    const int k = e >> 7, n = e & 127;
    const int d = n * 128 + ((((k >> 3) ^ (n & 7)) << 3)) + (k & 7);
    wsT01[d] = f2bf(Ws01[e]);
    wsT02[d] = f2bf(Ws02[e]);
    wsTA[d]  = f2bf(Ws[e]);
    wsTB[d]  = f2bf(Ws[128 * 128 + e]);
  }
  __syncthreads();

  const int lane = tid & 63;
  const int wv = tid >> 6;
  const int g = wv & 3;        // row group (16 rows)
  const int hh = wv >> 2;      // col half (64 cols)
  const int l15 = lane & 15, l4 = lane >> 4;
  const f32x4 zero4 = {0.f, 0.f, 0.f, 0.f};

  const int ntiles = (T + 63) >> 6;
  for (int tile = blockIdx.x; tile < ntiles; tile += gridDim.x) {
    const int rbase = tile << 6;
    f32x4 acc3[4] = {zero4, zero4, zero4, zero4};

    // ---- s01 path ----
    gather_p(h, M01, idx_ji, idx_ki, pbuf, rbase, T, tid, 0);
    __syncthreads();
    {
      f32x4 acc1[4] = {zero4, zero4, zero4, zero4};
      mfma_block4(pbuf, wsT01, acc1, g, hh, l15, l4);
      __syncthreads();                       // all reads of p01 done
      store_s(pbuf, acc1, bs01, g, hh, l15, l4);
    }
    __syncthreads();
    mfma_block4(pbuf, wsTA, acc3, g, hh, l15, l4);
    __syncthreads();                         // all reads of s01 done

    // ---- s02 path ----
    gather_p(h, M02, idx_ji, idx_ki, pbuf, rbase, T, tid, 128);
    __syncthreads();
    {
      f32x4 acc2[4] = {zero4, zero4, zero4, zero4};
      mfma_block4(pbuf, wsT02, acc2, g, hh, l15, l4);
      __syncthreads();
      store_s(pbuf, acc2, bs02, g, hh, l15, l4);
    }
    __syncthreads();
    mfma_block4(pbuf, wsTB, acc3, g, hh, l15, l4);

    // ---- epilogue: s = silu(acc3 + bs); scatter-add by idx_ji ----
    int jrow[4];
#pragma unroll
    for (int i = 0; i < 4; i++) {
      const int trow = rbase + 16 * g + 4 * l4 + i;
      jrow[i] = (trow < T) ? idx_ji[trow] : -1;
    }
#pragma unroll
    for (int ct = 0; ct < 4; ct++) {
      const int col = 64 * hh + 16 * ct + l15;
      const float bv = bs[col];
#pragma unroll
      for (int i = 0; i < 4; i++) {
        if (jrow[i] >= 0)
          atomicAdd(out_acc + (size_t)jrow[i] * 128 + col, silu_f(acc3[ct][i] + bv));
      }
    }
    __syncthreads();  // protect pbuf before next tile's gather
  }
}

extern "C" void kernel_launch(void* const* d_in, const int* in_sizes, int n_in,
                              void* d_out, int out_size, void* d_ws, size_t ws_size,
                              hipStream_t stream)
{
  const float* f    = (const float*)d_in[0];
  const float* M01  = (const float*)d_in[1];
  const float* M02  = (const float*)d_in[2];
  const float* W1   = (const float*)d_in[3];
  const float* b1   = (const float*)d_in[4];
  const float* W2   = (const float*)d_in[5];
  const float* b2   = (const float*)d_in[6];
  const float* Ws01 = (const float*)d_in[7];
  const float* bs01 = (const float*)d_in[8];
  const float* Ws02 = (const float*)d_in[9];
  const float* bs02 = (const float*)d_in[10];
  const float* Ws   = (const float*)d_in[11];
  const float* bs   = (const float*)d_in[12];
  const float* Wout = (const float*)d_in[13];
  const float* bout = (const float*)d_in[14];
  const int* idx_ji = (const int*)d_in[16];
  const int* idx_ki = (const int*)d_in[17];

  const int E = in_sizes[0] / 256;
  const int T = in_sizes[1] / 128;

  float* h = (float*)d_ws;          // [E][256] f32 (102.4 MB)
  float* out_acc = (float*)d_out;   // [E][128] f32 accumulator, then final out in-place

  const int mb = (E + 63) / 64;
  // edge MLP: h1 = silu(f@W1+b1); h = silu(h1@W2+b2) (in-place, row-block exclusive)
  gemm_rowtile<256, 1><<<mb, 256, 0, stream>>>(f, W1, b1, h, E, 256);
  gemm_rowtile<256, 1><<<mb, 256, 0, stream>>>(h, W2, b2, h, E, 256);

  hipMemsetAsync(d_out, 0, (size_t)E * 128 * sizeof(float), stream);

  const int ntiles = (T + 63) / 64;
  const int grid = ntiles < 512 ? ntiles : 512;
  triplet_fused<<<grid, 512, 0, stream>>>(h, M01, M02, Ws01, bs01, Ws02, bs02,
                                          Ws, bs, idx_ji, idx_ki, out_acc, T);

  // out = out_acc @ Wout + bout (in-place on d_out, row-block exclusive)
  gemm_rowtile<128, 0><<<mb, 256, 0, stream>>>(out_acc, Wout, bout, out_acc, E, 128);
}